// Round 12
// baseline (47.878 us; speedup 1.0000x reference)
//
#include <hip/hip_runtime.h>
#include <utility>

#define NQ 14
#define NST (1 << NQ)      // 16384
#define THREADS 1024
#define NP 16              // passes
#define NE 16              // elements per thread (4 local tile bits; 5th tile bit = lane-partner)

typedef float f2 __attribute__((ext_vector_type(2)));

// ---------------- compile-time schedule (5-bit tiles: 4 local + 1 lane bit) ----------------
struct PassD {
    unsigned short comboR[NE];  // RAW xor offsets over LOCAL tile bits 0-3
    unsigned short rows[5];     // R row (parity mask) per tile bit (4 local + 1 lane)
    unsigned short tmask[5];    // C column per tile bit
    unsigned short crx_widx[4];
    unsigned short ry_widx[4];
    unsigned char  ry_tb[4];
    unsigned char  ncrx;        // 2 or 4 (gate 3 targets the lane bit)
    unsigned char  nry;
    short          rzidx;
    unsigned char  measfold;
};
struct RZD  { unsigned short rows_ng[9]; unsigned short widx_ng[9]; unsigned short widx_g[5]; };
struct AllD { PassD pass[NP]; RZD rz[4]; unsigned short meas_rows_ng[9]; int npass; };

constexpr void fill_geom(PassD& P, const unsigned short* R, const unsigned short* C, const int* tb)
{
    for (int i = 0; i < 5; ++i) { P.tmask[i] = C[tb[i]]; P.rows[i] = R[tb[i]]; }
    for (int j = 0; j < NE; ++j) {
        unsigned short x = 0;
        for (int i = 0; i < 4; ++i) if ((j >> i) & 1) x = (unsigned short)(x ^ P.tmask[i]);
        P.comboR[j] = x;
    }
}

constexpr void ring(unsigned short* R, unsigned short* C) {
    for (int q = 0; q < NQ; ++q) {
        int cb = 13 - q, tb = 13 - ((q + 1) % NQ);
        R[tb] = (unsigned short)(R[tb] ^ R[cb]);
        C[cb] = (unsigned short)(C[cb] ^ C[tb]);
    }
}

constexpr AllD build_desc() {
    AllD A{};
    unsigned short R[NQ] = {}, C[NQ] = {};
    for (int k = 0; k < NQ; ++k) { R[k] = (unsigned short)(1u << k); C[k] = (unsigned short)(1u << k); }
    int np = 0;
    const int tiles[4][5]  = {{13,12,11,10,9},{9,8,7,6,5},{5,4,3,2,1},{1,0,13,3,2}};
    const int gfirst[4]    = {0, 4, 8, 12};
    const int ngate[4]     = {4, 4, 4, 2};
    const int rybits[4][4] = {{12,11,10,0},{9,8,7,6},{5,4,3,2},{13,1,0,0}};
    const int nryp[4]      = {3, 4, 4, 3};

    for (int blk = 0; blk < 4; ++blk) {
        ring(R, C);   // CNOT ring = pure relabeling
        for (int pi = 0; pi < 4; ++pi) {
            PassD& P = A.pass[np];
            fill_geom(P, R, C, tiles[pi]);
            P.ncrx = (unsigned char)ngate[pi];
            for (int g = 0; g < 4; ++g)
                P.crx_widx[g] = (unsigned short)((g < ngate[pi]) ? blk*42 + 28 + gfirst[pi] + g : 0);
            if (blk < 3) {
                P.nry = (unsigned char)nryp[pi];
                for (int g = 0; g < 4; ++g) {
                    if (g < nryp[pi]) {
                        int k = rybits[pi][g];
                        P.ry_widx[g] = (unsigned short)((blk + 1)*42 + (13 - k));
                        int t = 0;
                        for (int i = 0; i < 5; ++i) if (tiles[pi][i] == k) t = i;
                        P.ry_tb[g] = (unsigned char)t;
                    } else { P.ry_widx[g] = 0; P.ry_tb[g] = 0; }
                }
            } else { P.nry = 0; for (int g = 0; g < 4; ++g) { P.ry_widx[g] = 0; P.ry_tb[g] = 0; } }
            P.rzidx = (short)((pi == 0) ? blk : -1);
            P.measfold = (unsigned char)((blk == 3 && pi == 3) ? 1 : 0);
            if (pi == 0) {
                RZD& Z = A.rz[blk];
                for (int i = 0; i < 5; ++i)
                    Z.widx_g[i] = (unsigned short)(blk*42 + 14 + (13 - tiles[0][i]));
                int t = 0;
                for (int q = 5; q < NQ; ++q, ++t) {
                    Z.rows_ng[t] = R[13 - q];
                    Z.widx_ng[t] = (unsigned short)(blk*42 + 14 + q);
                }
            }
            ++np;
        }
        if (blk == 3)
            for (int t = 0; t < 9; ++t) A.meas_rows_ng[t] = R[13 - (1 + t)];  // qubits 1..9
    }
    A.npass = np;
    return A;
}

constexpr AllD A = build_desc();
static_assert(A.npass == NP, "expected 16 passes");

constexpr int parity14(unsigned v) { v ^= v >> 8; v ^= v >> 4; v ^= v >> 2; v ^= v >> 1; return (int)(v & 1); }

constexpr bool check_dual() {
    for (int p = 0; p < NP; ++p)
        for (int i = 0; i < 5; ++i)
            for (int j = 0; j < 5; ++j)
                if (parity14((unsigned)(A.pass[p].rows[i] & A.pass[p].tmask[j])) != (i == j ? 1 : 0))
                    return false;
    return true;
}
static_assert(check_dual(), "R/C duality violated");

constexpr bool check_ry() {
    for (int p = 0; p < NP; ++p)
        for (int g = 0; g < A.pass[p].nry; ++g)
            if (A.pass[p].ry_tb[g] > 3) return false;
    return true;
}
static_assert(check_ry(), "RY fold on lane bit not supported");

struct GWT { unsigned short w[NP][8]; };
constexpr GWT build_gwt() {
    GWT g{};
    for (int p = 0; p < NP; ++p) {
        for (int s = 0; s < 4; ++s) g.w[p][s]     = A.pass[p].crx_widx[s];
        for (int s = 0; s < 4; ++s) g.w[p][4 + s] = A.pass[p].ry_widx[s];
    }
    return g;
}
constexpr GWT GW = build_gwt();

// ---------------- GF(2) machinery ----------------
constexpr int lead(unsigned short v) { int b = 13; while (b > 0 && !((v >> b) & 1)) --b; return b; }

struct Span {
    unsigned short red[14]; int n;
    constexpr unsigned short reduce(unsigned short v) const {
        for (int i = 0; i < n; ++i) { int lb = lead(red[i]); if ((v >> lb) & 1) v = (unsigned short)(v ^ red[i]); }
        return v;
    }
    constexpr bool add(unsigned short v) {
        unsigned short r = reduce(v);
        if (!r) return false;
        red[n++] = r; return true;
    }
};

// M-projection over the 4 LOCAL tile bits only (projecting the lane bit would
// collide partner threads). The 5th parity stays runtime -> LUT bit s4.
constexpr unsigned short proj(unsigned short vec, const PassD& P) {
    unsigned short r = vec;
    for (int t = 0; t < 4; ++t)
        if (parity14((unsigned)(vec & P.rows[t]))) r = (unsigned short)(r ^ P.tmask[t]);
    return r;
}

// ---- lane/wave vectors: lane[0] forced = tmask[4] (partner direction in lane span) ----
struct VecsT { unsigned short lane[NP][6]; unsigned short g[NP/2][4]; int ok; };
constexpr VecsT build_vecs() {
    VecsT V{}; V.ok = 1;
    for (int k = 0; k < NP/2; ++k) {
        const PassD& P0 = A.pass[2*k];
        const PassD& P1 = A.pass[2*k + 1];
        Span SW{}; unsigned short Wb[10] = {}; int nw = 0;
        for (int i = 0; i < 5; ++i) if (SW.add(P0.tmask[i])) Wb[nw++] = P0.tmask[i];
        for (int i = 0; i < 5; ++i) if (nw < 10 && SW.add(P1.tmask[i])) Wb[nw++] = P1.tmask[i];
        for (int b = 0; b < 14 && nw < 10; ++b) {
            unsigned short e = (unsigned short)(1u << b);
            if (SW.add(e)) Wb[nw++] = e;
        }
        if (nw != 10) V.ok = 0;
        Span SG = SW; int ngv = 0;
        for (int b = 0; b < 14 && ngv < 4; ++b) {
            unsigned short e = (unsigned short)(1u << b);
            if (SG.add(e)) V.g[k][ngv++] = e;
        }
        if (ngv != 4) V.ok = 0;
        for (int pp = 0; pp < 2; ++pp) {
            const PassD& P = (pp == 0) ? P0 : P1;
            int pidx = 2*k + pp;
            Span ST{};
            for (int i = 0; i < 4; ++i) ST.add(P.tmask[i]);     // local tile span
            int nl = 0;
            if (ST.add(P.tmask[4])) V.lane[pidx][nl++] = P.tmask[4];
            else V.ok = 0;
            for (int i = 0; i < 10 && nl < 6; ++i)
                if (ST.add(Wb[i])) V.lane[pidx][nl++] = Wb[i];
            if (nl != 6) V.ok = 0;
            Span SF{};
            for (int i = 0; i < 4; ++i) SF.add(P.tmask[i]);
            for (int i = 0; i < 6; ++i) if (!SF.add(V.lane[pidx][i])) V.ok = 0;
            for (int i = 0; i < 4; ++i) if (!SF.add(V.g[k][i])) V.ok = 0;
            if (SF.n != 14) V.ok = 0;
        }
    }
    return V;
}
constexpr VecsT VC = build_vecs();
static_assert(VC.ok == 1, "vec construction failed");

struct P6T { unsigned short u[NP][6]; };
constexpr P6T build_p6() {
    P6T X{};
    for (int p = 0; p < NP; ++p)
        for (int i = 0; i < 6; ++i)
            X.u[p][i] = proj(VC.lane[p][i], A.pass[p]);
    return X;
}
constexpr P6T P6 = build_p6();

// ---- bank map L' : F2^14 -> F2^4 ----
constexpr unsigned lmap(const unsigned short* row, unsigned x) {
    unsigned l = 0;
    for (int t = 0; t < 4; ++t) l |= (unsigned)parity14(row[t] & x) << t;
    return l;
}
constexpr int nib_rank(const unsigned* nibs, int n) {
    unsigned basis[4] = {};
    int r = 0;
    for (int i = 0; i < n; ++i) {
        unsigned v = nibs[i] & 15u;
        for (int b = 3; b >= 0 && v; --b) {
            if (!((v >> b) & 1)) continue;
            if (basis[b]) v ^= basis[b];
            else { basis[b] = v; ++r; v = 0; }
        }
    }
    return r;
}
struct Lp { unsigned short row[4]; int score; };

constexpr int full_score(const unsigned short* r) {
    unsigned cn[4] = {};
    for (int c = 0; c < 4; ++c) {
        unsigned v = 0;
        for (int t = 0; t < 4; ++t) v |= ((unsigned)(r[t] >> c) & 1u) << t;
        cn[c] = v;
    }
    if (nib_rank(cn, 4) != 4) return -1;
    int sc = 0;
    for (int p = 0; p < NP; ++p) {
        unsigned im[6] = {};
        for (int i = 0; i < 6; ++i) im[i] = lmap(r, P6.u[p][i]);
        if (nib_rank(im, 6) == 4) ++sc;
    }
    return sc;
}

constexpr Lp search_stage(unsigned seed, int iters) {
    Lp best{}; best.score = -1;
    unsigned s = seed;
    for (int it = 0; it < iters; ++it) {
        unsigned short r[4] = {};
        for (int t = 0; t < 4; ++t) { s = s*1664525u + 1013904223u; r[t] = (unsigned short)((s >> 9) & 0x3FFF); }
        int sc = full_score(r);
        if (sc > best.score) { best.score = sc; for (int t = 0; t < 4; ++t) best.row[t] = r[t]; }
        if (best.score == NP) break;
    }
    return best;
}
constexpr Lp S0 = search_stage(0x12345u, 400);
constexpr Lp S1 = search_stage(0xBEEF1u, 400);
constexpr Lp S2 = search_stage(0xC0FFEu, 400);
constexpr Lp S3 = search_stage(0x777A1u, 400);
constexpr Lp S4 = search_stage(0x51DE5u, 400);
constexpr Lp S5 = search_stage(0xA11CEu, 400);
constexpr Lp S6 = search_stage(0x0F00Du, 400);
constexpr Lp S7 = search_stage(0x13579u, 400);
constexpr Lp pick_best() {
    Lp b = S0;
    if (S1.score > b.score) b = S1;
    if (S2.score > b.score) b = S2;
    if (S3.score > b.score) b = S3;
    if (S4.score > b.score) b = S4;
    if (S5.score > b.score) b = S5;
    if (S6.score > b.score) b = S6;
    if (S7.score > b.score) b = S7;
    return b;
}
constexpr Lp climb(Lp start, int sweeps) {
    Lp cur = start;
    for (int sw = 0; sw < sweeps && cur.score < NP; ++sw) {
        for (int t = 0; t < 4; ++t) {
            for (int b = 0; b < 14; ++b) {
                if (cur.score >= NP) break;
                unsigned short nr[4] = {cur.row[0], cur.row[1], cur.row[2], cur.row[3]};
                nr[t] = (unsigned short)(nr[t] ^ (1u << b));
                int sc = full_score(nr);
                if (sc > cur.score) { cur.score = sc; cur.row[t] = nr[t]; }
            }
        }
    }
    return cur;
}
constexpr Lp C0 = climb(pick_best(), 2);
constexpr Lp C1 = climb(C0, 2);
constexpr Lp LSEL = C1;
static_assert(LSEL.score >= 13, "bank-map search failed badly");

constexpr unsigned short swz2(unsigned short x) {
    return (unsigned short)(((unsigned)x & ~15u) | lmap(LSEL.row, x));
}

// ---- lane-basis canonicalization: slot-map kernel -> lane bits 4,5 ----
constexpr int add_basis4(unsigned* basis, unsigned v) {
    for (int b = 3; b >= 0; --b) {
        if (!((v >> b) & 1)) continue;
        if (basis[b]) v ^= basis[b];
        else { basis[b] = v; return 1; }
    }
    return 0;
}
constexpr int add_basis6(unsigned* basis, unsigned v) {
    for (int b = 5; b >= 0; --b) {
        if (!((v >> b) & 1)) continue;
        if (basis[b]) v ^= basis[b];
        else { basis[b] = v; return 1; }
    }
    return 0;
}
struct LaneOrd { unsigned short lane[NP][6]; };
constexpr LaneOrd build_lane2() {
    LaneOrd O{};
    for (int p = 0; p < NP; ++p) {
        for (int i = 0; i < 6; ++i) O.lane[p][i] = VC.lane[p][i];
        unsigned imu[6] = {};
        for (int i = 0; i < 6; ++i) imu[i] = lmap(LSEL.row, P6.u[p][i]);
        {
            unsigned chk[6] = {imu[0], imu[1], imu[2], imu[3], imu[4], imu[5]};
            if (nib_rank(chk, 6) != 4) continue;   // fallback: keep default order
        }
        unsigned short nl[6] = {};
        int ns = 0;
        unsigned ib[4] = {};
        unsigned sb[6] = {};
        for (unsigned c = 1; c < 64 && ns < 4; ++c) {
            unsigned img = 0; unsigned short rv = 0;
            for (int i = 0; i < 6; ++i) if ((c >> i) & 1) { img ^= imu[i]; rv = (unsigned short)(rv ^ VC.lane[p][i]); }
            if (img == 0) continue;
            unsigned ib2[4] = {ib[0], ib[1], ib[2], ib[3]};
            unsigned sb2[6] = {sb[0], sb[1], sb[2], sb[3], sb[4], sb[5]};
            if (add_basis4(ib2, img) && add_basis6(sb2, c)) {
                for (int t = 0; t < 4; ++t) ib[t] = ib2[t];
                for (int t = 0; t < 6; ++t) sb[t] = sb2[t];
                nl[ns++] = rv;
            }
        }
        for (unsigned c = 1; c < 64 && ns < 6; ++c) {
            unsigned img = 0; unsigned short rv = 0;
            for (int i = 0; i < 6; ++i) if ((c >> i) & 1) { img ^= imu[i]; rv = (unsigned short)(rv ^ VC.lane[p][i]); }
            if (img != 0) continue;
            unsigned sb2[6] = {sb[0], sb[1], sb[2], sb[3], sb[4], sb[5]};
            if (add_basis6(sb2, c)) {
                for (int t = 0; t < 6; ++t) sb[t] = sb2[t];
                nl[ns++] = rv;
            }
        }
        if (ns == 6)
            for (int i = 0; i < 6; ++i) O.lane[p][i] = nl[i];
    }
    return O;
}
constexpr LaneOrd LO = build_lane2();

// ---- shuffle masks: combo c of FINAL lane basis with sum == tmask[4] ----
struct SHMt { int m[NP]; int ok; };
constexpr SHMt build_shm() {
    SHMt S{}; S.ok = 1;
    for (int p = 0; p < NP; ++p) {
        S.m[p] = 0;
        if (A.pass[p].ncrx < 4) continue;
        int found = 0;
        for (unsigned c = 1; c < 64 && !found; ++c) {
            unsigned short x = 0;
            for (int i = 0; i < 6; ++i) if ((c >> i) & 1) x = (unsigned short)(x ^ LO.lane[p][i]);
            if (x == A.pass[p].tmask[4]) { S.m[p] = (int)c; found = 1; }
        }
        if (!found) S.ok = 0;
    }
    return S;
}
constexpr SHMt SHM = build_shm();
static_assert(SHM.ok == 1, "shuffle mask not found");

// pre-swizzled combo offsets (16 local combos)
struct CS2 { unsigned short c[NP][NE]; };
constexpr CS2 build_cs2() {
    CS2 C{};
    for (int p = 0; p < NP; ++p)
        for (int j = 0; j < NE; ++j)
            C.c[p][j] = swz2(A.pass[p].comboR[j]);
    return C;
}
constexpr CS2 CSS = build_cs2();

struct LJt { unsigned short v[NE]; };
constexpr LJt build_lj() {
    LJt t{};
    for (int j = 0; j < NE; ++j) t.v[j] = (unsigned short)lmap(LSEL.row, (unsigned)(j * THREADS));
    return t;
}
constexpr LJt LJ = build_lj();

// entry = (swz2(proj4(vec))<<3) | (par << 22); par: bits 0-8 = ng parities, bit 9 = s4 (lane-bit side)
constexpr unsigned pack_entry(unsigned short vec0, int p) {
    const PassD& P = A.pass[p];
    unsigned short vec = proj(vec0, P);
    unsigned par = 0;
    if (P.rzidx >= 0)
        for (int t = 0; t < 9; ++t) par |= (unsigned)parity14(vec & A.rz[P.rzidx].rows_ng[t]) << t;
    if (P.measfold)
        for (int t = 0; t < 9; ++t) par |= (unsigned)parity14(vec & A.meas_rows_ng[t]) << t;
    par |= (unsigned)parity14(vec & P.rows[4]) << 9;
    return ((unsigned)swz2(vec) << 3) | (par << 22);
}

// LUT0: tid bits 0-4 (lanes 0-4); LUT1: tid bits 5-9 (lane 5 + wave g[0..3])
struct LutsT { unsigned v[NP][2][32]; };
constexpr LutsT build_luts() {
    LutsT L{};
    for (int p = 0; p < NP; ++p) {
        int k = p >> 1;
        for (int t = 0; t < 32; ++t) {
            unsigned short x = 0;
            for (int i = 0; i < 5; ++i) if ((t >> i) & 1) x = (unsigned short)(x ^ LO.lane[p][i]);
            L.v[p][0][t] = pack_entry(x, p);
            unsigned short y = 0;
            if (t & 1) y = (unsigned short)(y ^ LO.lane[p][5]);
            for (int i = 0; i < 4; ++i) if ((t >> (i + 1)) & 1) y = (unsigned short)(y ^ VC.g[k][i]);
            L.v[p][1][t] = pack_entry(y, p);
        }
    }
    return L;
}
constexpr LutsT LUTS = build_luts();
__device__ __constant__ LutsT cLUTS = LUTS;

// ---------------- per-pass device code ----------------
template<int Pi>
__device__ __forceinline__ void run_pass(f2* st, const f2 (*tabG)[8], const float (*tabRZ)[14],
                                         unsigned comb, float* acc)
{
    constexpr PassD Pd = A.pass[Pi];
    char* stb = (char*)st;
    const int base = (int)(comb & 0x1FFF8u);
    const unsigned par = comb >> 22;          // 9 ng bits + s4 at bit 9

    f2 v[NE];
#pragma unroll
    for (int j = 0; j < NE; ++j)
        v[j] = *(const f2*)(stb + (base ^ (CSS.c[Pi][j] << 3)));

    // ---- fused RZ layer ----
    if constexpr (Pd.rzidx >= 0) {
        float phi0 = 0.f;
#pragma unroll
        for (int t = 0; t < 9; ++t) {
            float h = tabRZ[Pd.rzidx][t];
            phi0 += ((par >> t) & 1) ? h : -h;
        }
        { float h = tabRZ[Pd.rzidx][13]; phi0 += ((par >> 9) & 1) ? h : -h; }  // lane-bit group qubit
        const float h0 = tabRZ[Pd.rzidx][9],  h1 = tabRZ[Pd.rzidx][10];
        const float h2 = tabRZ[Pd.rzidx][11], h3 = tabRZ[Pd.rzidx][12];
#pragma unroll
        for (int j = 0; j < NE; ++j) {
            float phi = ((((phi0 + ((j & 1) ? h0 : -h0)) + ((j & 2) ? h1 : -h1))
                                 + ((j & 4) ? h2 : -h2)) + ((j & 8) ? h3 : -h3));
            float s, c; __sincosf(phi, &s, &c);
            f2 C = {c, c}, S = {-s, s};
            v[j] = C * v[j] + S * v[j].yx;
        }
    }

    // ---- CRX local gates (0..2): control bit g, target bit g+1, both thread-local ----
#pragma unroll
    for (int g = 0; g < (Pd.ncrx < 3 ? (int)Pd.ncrx : 3); ++g) {
        f2 cs = tabG[Pi][g];
        f2 C = {cs.x, cs.x}, S = {cs.y, -cs.y};
#pragma unroll
        for (int j = 0; j < NE; ++j) if (((j >> g) & 1) && !((j >> (g + 1)) & 1)) {
            int j1 = j | (1 << (g + 1));
            f2 a0 = v[j], a1 = v[j1];
            v[j]  = C * a0 + S * a1.yx;
            v[j1] = C * a1 + S * a0.yx;
        }
    }
    // ---- CRX gate 3: control local bit 3, target = lane-partner bit (shuffle) ----
    if constexpr (Pd.ncrx == 4) {
        constexpr int sm = SHM.m[Pi];
        f2 cs = tabG[Pi][3];
        f2 C = {cs.x, cs.x}, S = {cs.y, -cs.y};
#pragma unroll
        for (int j = 8; j < 16; ++j) {       // logical control (bit 3) == 1
            f2 pv;
            pv.x = __shfl_xor(v[j].x, sm, 64);
            pv.y = __shfl_xor(v[j].y, sm, 64);
            // RX symmetric: both sides apply new = C*own + S*partner.yx
            v[j] = C * v[j] + S * pv.yx;
        }
    }

    // ---- folded next-block RY gates (local positions only) ----
#pragma unroll
    for (int g = 0; g < Pd.nry; ++g) {
        int t = Pd.ry_tb[g];
        f2 cs = tabG[Pi][4 + g];
        f2 C = {cs.x, cs.x}, Sv = {cs.y, cs.y}, NS = {-cs.y, -cs.y};
#pragma unroll
        for (int j = 0; j < NE; ++j) if (!((j >> t) & 1)) {
            int j1 = j | (1 << t);
            f2 a0 = v[j], a1 = v[j1];
            v[j]  = C * a0 + NS * a1;
            v[j1] = Sv * a0 + C * a1;
        }
    }

    if constexpr (Pd.measfold != 0) {
        f2 ps = {0.f, 0.f}, p0 = {0.f, 0.f}, p1 = {0.f, 0.f}, p2 = {0.f, 0.f}, p3 = {0.f, 0.f};
#pragma unroll
        for (int j = 0; j < NE; ++j) {
            f2 t2 = v[j] * v[j];
            ps += t2;
            if (j & 1) p0 += t2;
            if (j & 2) p1 += t2;
            if (j & 4) p2 += t2;
            if (j & 8) p3 += t2;
        }
        float psum = ps.x + ps.y;
        float pg0 = p0.x + p0.y, pg1 = p1.x + p1.y, pg2 = p2.x + p2.y, pg3 = p3.x + p3.y;
        // local tile bits {1,0,13,3} = qubits {12,13,0,10} (canonical, signs +1)
        acc[12] += psum - 2.f * pg0;
        acc[13] += psum - 2.f * pg1;
        acc[0]  += psum - 2.f * pg2;
        acc[10] += psum - 2.f * pg3;
        // lane-bit qubit 11: side bit s4
        float s4 = ((par >> 9) & 1) ? -1.f : 1.f;
        acc[11] += s4 * psum;
#pragma unroll
        for (int t = 0; t < 9; ++t) {
            float sg = ((par >> t) & 1) ? -1.f : 1.f;
            acc[1 + t] += sg * psum;
        }
    } else {
#pragma unroll
        for (int j = 0; j < NE; ++j)
            *(f2*)(stb + (base ^ (CSS.c[Pi][j] << 3))) = v[j];
        if constexpr ((Pi & 1) != 0) __syncthreads();
    }
}

template<int... I>
__device__ __forceinline__ void run_all(std::integer_sequence<int, I...>,
                                        f2* st, const f2 (*tabG)[8], const float (*tabRZ)[14],
                                        const unsigned* comb, float* acc)
{
    (run_pass<I>(st, tabG, tabRZ, comb[I], acc), ...);
}

// ---------------- main kernel ----------------
// 1024 threads (16 waves, 4/SIMD); LDS caps 1 block/CU -> VGPR cap 128.
__global__ __launch_bounds__(THREADS, 4)
void qsim_kernel(const float* __restrict__ inputs,
                 const float* __restrict__ weights,
                 float* __restrict__ out)
{
    __shared__ f2     st[NST];           // 128 KiB state
    __shared__ float  tab[256];
    __shared__ f2     tabG[NP][8];
    __shared__ float  tabRZ[4][14];      // [0..8] ng, [9..12] local group, [13] lane group
    __shared__ float  red[THREADS / 64][NQ];

    const int b = blockIdx.x;
    const int tid = threadIdx.x;

    unsigned comb[NP];
#pragma unroll
    for (int p = 0; p < NP; ++p)
        comb[p] = cLUTS.v[p][0][tid & 31] ^ cLUTS.v[p][1][tid >> 5];

    // ---- build trig + product tables (disjoint thread ranges) ----
    if (tid < 128) {
        int p = tid >> 3, sl = tid & 7;
        float w = weights[GW.w[p][sl]];
        float s, c; __sincosf(0.5f * w, &s, &c);
        tabG[p][sl] = (f2){c, s};
    } else if (tid >= 128 && tid < 128 + 56) {
        int idx = tid - 128;
        int blk = idx / 14, k = idx - blk * 14;
        unsigned wi = (k < 9) ? A.rz[blk].widx_ng[k] : A.rz[blk].widx_g[k - 9];
        tabRZ[blk][k] = 0.5f * weights[wi];
    } else if (tid >= 256 && tid < 512) {
        int t = tid - 256;
        int half = t >> 7, tt = t & 127;
        float prod = 1.f;
#pragma unroll
        for (int j = 0; j < 7; ++j) {
            int xb = j + 7 * half;
            int q  = 13 - xb;
            float a = 0.5f * (inputs[b * NQ + q] + weights[q]);   // init RY ∘ blk0 RY fold
            float s, c; __sincosf(a, &s, &c);
            prod *= ((tt >> j) & 1) ? s : c;
        }
        tab[t] = prod;
    }
    __syncthreads();

    // ---- write product state with swz2 ----
    unsigned l4t = 0;
#pragma unroll
    for (int t = 0; t < 4; ++t)
        l4t |= (unsigned)(__popc((int)(LSEL.row[t] & tid)) & 1) << t;
#pragma unroll
    for (int j = 0; j < NE; ++j) {
        int x = tid + j * THREADS;
        int addr = (x & ~15) | (int)(l4t ^ LJ.v[j]);
        st[addr] = (f2){tab[x & 127] * tab[128 + (x >> 7)], 0.f};
    }
    __syncthreads();

    float acc[NQ];
#pragma unroll
    for (int q = 0; q < NQ; ++q) acc[q] = 0.f;

    run_all(std::make_integer_sequence<int, NP>{}, st, tabG, tabRZ, comb, acc);

    // ---- block-wide reduction ----
#pragma unroll
    for (int q = 0; q < NQ; ++q) {
        float v2 = acc[q];
        v2 += __shfl_down(v2, 32);
        v2 += __shfl_down(v2, 16);
        v2 += __shfl_down(v2, 8);
        v2 += __shfl_down(v2, 4);
        v2 += __shfl_down(v2, 2);
        v2 += __shfl_down(v2, 1);
        acc[q] = v2;
    }
    const int wave = tid >> 6, lane = tid & 63;
    if (lane == 0) {
#pragma unroll
        for (int q = 0; q < NQ; ++q) red[wave][q] = acc[q];
    }
    __syncthreads();
    if (tid < NQ) {
        float v2 = 0.f;
#pragma unroll
        for (int w = 0; w < THREADS / 64; ++w) v2 += red[w][tid];
        out[b * NQ + tid] = v2;
    }
}

extern "C" void kernel_launch(void* const* d_in, const int* in_sizes, int n_in,
                              void* d_out, int out_size, void* d_ws, size_t ws_size,
                              hipStream_t stream) {
    const float* inputs  = (const float*)d_in[0];
    const float* weights = (const float*)d_in[1];
    float* out = (float*)d_out;
    const int B = in_sizes[0] / NQ;   // 256
    qsim_kernel<<<dim3(B), dim3(THREADS), 0, stream>>>(inputs, weights, out);
}

// Round 13
// 44.635 us; speedup vs baseline: 1.0727x; 1.0727x over previous
//
#include <hip/hip_runtime.h>
#include <utility>

#define NQ 14
#define NST (1 << NQ)      // 16384
#define THREADS 1024
#define NP 16              // passes
#define NE 16              // elements per thread (4 local bits; tile bit 0 = lane/control-only)

typedef float f2 __attribute__((ext_vector_type(2)));

// ---------------- compile-time schedule ----------------
// Tile position 0 = first chain bit = CONTROL-ONLY = lane (cross-thread) bit.
// Positions 1..4 = thread-local bits L0..L3.
struct PassD {
    unsigned short comboR[NE];  // RAW xor offsets over LOCAL bits (positions 1..4)
    unsigned short rows[5];     // R row (parity mask); [0] = lane bit
    unsigned short tmask[5];    // C column; [0] = lane bit
    unsigned short crx_widx[4]; // [0] = gate0 (lane-ctrl), [1..3] = local chain gates
    unsigned short ry_widx[4];
    unsigned short shry_widx;   // shuffle-RY (on lane bit) weight index
    unsigned char  ry_tb[4];    // local position (0..3)
    unsigned char  ngl;         // local chain gates (3 or 2)
    unsigned char  has_g0;
    unsigned char  has_shry;
    unsigned char  nry;
    short          rzidx;
    unsigned char  measfold;
};
struct RZD  { unsigned short rows_ng[9]; unsigned short widx_ng[9]; unsigned short widx_g[5]; };
struct AllD { PassD pass[NP]; RZD rz[4]; unsigned short meas_rows_ng[9]; int npass; };

constexpr void fill_geom(PassD& P, const unsigned short* R, const unsigned short* C, const int* tb)
{
    for (int i = 0; i < 5; ++i) { P.tmask[i] = C[tb[i]]; P.rows[i] = R[tb[i]]; }
    for (int j = 0; j < NE; ++j) {
        unsigned short x = 0;
        for (int i = 1; i < 5; ++i) if ((j >> (i - 1)) & 1) x = (unsigned short)(x ^ P.tmask[i]);
        P.comboR[j] = x;
    }
}

constexpr void ring(unsigned short* R, unsigned short* C) {
    for (int q = 0; q < NQ; ++q) {
        int cb = 13 - q, tb = 13 - ((q + 1) % NQ);
        R[tb] = (unsigned short)(R[tb] ^ R[cb]);
        C[cb] = (unsigned short)(C[cb] ^ C[tb]);
    }
}

constexpr AllD build_desc() {
    AllD A{};
    unsigned short R[NQ] = {}, C[NQ] = {};
    for (int k = 0; k < NQ; ++k) { R[k] = (unsigned short)(1u << k); C[k] = (unsigned short)(1u << k); }
    int np = 0;
    // chain chunks (4,4,4,2); tile[0] = first control (lane). Pass 3: lane = filler bit 9.
    const int tiles[4][5]  = {{13,12,11,10,9},{9,8,7,6,5},{5,4,3,2,1},{9,1,0,13,5}};
    // RY folds (next-block): bits completing in each pass, placed on LOCAL positions.
    const int fb[4][4] = {{12,11,10,0},{8,7,6,0},{4,3,2,0},{1,0,13,5}};
    const int nf[4]    = {3,3,3,4};

    for (int blk = 0; blk < 4; ++blk) {
        ring(R, C);   // CNOT ring = pure relabeling
        for (int pi = 0; pi < 4; ++pi) {
            PassD& P = A.pass[np];
            fill_geom(P, R, C, tiles[pi]);
            if (pi < 3) {
                P.has_g0 = 1; P.ngl = 3;
                for (int g = 0; g < 4; ++g) P.crx_widx[g] = (unsigned short)(blk*42 + 28 + 4*pi + g);
            } else {
                P.has_g0 = 0; P.ngl = 2;
                P.crx_widx[0] = 0;
                P.crx_widx[1] = (unsigned short)(blk*42 + 28 + 12);
                P.crx_widx[2] = (unsigned short)(blk*42 + 28 + 13);
                P.crx_widx[3] = 0;
            }
            if (blk < 3) {
                P.nry = (unsigned char)nf[pi];
                for (int g = 0; g < 4; ++g) {
                    if (g < nf[pi]) {
                        int k = fb[pi][g];
                        P.ry_widx[g] = (unsigned short)((blk + 1)*42 + (13 - k));
                        int t = 0;
                        for (int i = 1; i < 5; ++i) if (tiles[pi][i] == k) t = i - 1;
                        P.ry_tb[g] = (unsigned char)t;
                    } else { P.ry_widx[g] = 0; P.ry_tb[g] = 0; }
                }
                P.has_shry = (unsigned char)((pi == 3) ? 1 : 0);
                P.shry_widx = (unsigned short)((blk + 1)*42 + 4);   // RY on bit 9 (qubit 4)
            } else {
                P.nry = 0; P.has_shry = 0; P.shry_widx = 0;
                for (int g = 0; g < 4; ++g) { P.ry_widx[g] = 0; P.ry_tb[g] = 0; }
            }
            P.rzidx = (short)((pi == 0) ? blk : -1);
            P.measfold = (unsigned char)((blk == 3 && pi == 3) ? 1 : 0);
            if (pi == 0) {
                RZD& Z = A.rz[blk];
                // group: locals L0..L3 = bits {12,11,10,9} -> qubits 1..4; lane bit 13 -> qubit 0
                for (int i = 0; i < 4; ++i)
                    Z.widx_g[i] = (unsigned short)(blk*42 + 14 + (13 - tiles[0][i + 1]));
                Z.widx_g[4] = (unsigned short)(blk*42 + 14 + 0);
                int t = 0;
                for (int q = 5; q < NQ; ++q, ++t) {      // non-group qubits 5..13
                    Z.rows_ng[t] = R[13 - q];
                    Z.widx_ng[t] = (unsigned short)(blk*42 + 14 + q);
                }
            }
            ++np;
        }
        if (blk == 3) {
            const int MQ[9] = {1,2,3,5,6,7,9,10,11};
            for (int t = 0; t < 9; ++t) A.meas_rows_ng[t] = R[13 - MQ[t]];
        }
    }
    A.npass = np;
    return A;
}

constexpr AllD A = build_desc();
static_assert(A.npass == NP, "expected 16 passes");

constexpr int parity14(unsigned v) { v ^= v >> 8; v ^= v >> 4; v ^= v >> 2; v ^= v >> 1; return (int)(v & 1); }

constexpr bool check_dual() {
    for (int p = 0; p < NP; ++p)
        for (int i = 0; i < 5; ++i)
            for (int j = 0; j < 5; ++j)
                if (parity14((unsigned)(A.pass[p].rows[i] & A.pass[p].tmask[j])) != (i == j ? 1 : 0))
                    return false;
    return true;
}
static_assert(check_dual(), "R/C duality violated");

constexpr bool check_ry() {
    for (int p = 0; p < NP; ++p)
        for (int g = 0; g < A.pass[p].nry; ++g)
            if (A.pass[p].ry_tb[g] > 3) return false;
    return true;
}
static_assert(check_ry(), "RY fold must be on local position");

// gate table slots: 0=gate0, 1..3=local gates (slot3 doubles as shuffle-RY on pass3), 4..7=RY folds
struct GWT { unsigned short w[NP][8]; };
constexpr GWT build_gwt() {
    GWT g{};
    for (int p = 0; p < NP; ++p) {
        g.w[p][0] = A.pass[p].crx_widx[0];
        g.w[p][1] = A.pass[p].crx_widx[1];
        g.w[p][2] = A.pass[p].crx_widx[2];
        g.w[p][3] = A.pass[p].has_shry ? A.pass[p].shry_widx : A.pass[p].crx_widx[3];
        for (int s = 0; s < 4; ++s) g.w[p][4 + s] = A.pass[p].ry_widx[s];
    }
    return g;
}
constexpr GWT GW = build_gwt();

// ---------------- GF(2) machinery ----------------
constexpr int lead(unsigned short v) { int b = 13; while (b > 0 && !((v >> b) & 1)) --b; return b; }

struct Span {
    unsigned short red[14]; int n;
    constexpr unsigned short reduce(unsigned short v) const {
        for (int i = 0; i < n; ++i) { int lb = lead(red[i]); if ((v >> lb) & 1) v = (unsigned short)(v ^ red[i]); }
        return v;
    }
    constexpr bool add(unsigned short v) {
        unsigned short r = reduce(v);
        if (!r) return false;
        red[n++] = r; return true;
    }
};

// M-projection over the 4 LOCAL bits only; lane-bit parity stays runtime (s4).
constexpr unsigned short proj(unsigned short vec, const PassD& P) {
    unsigned short r = vec;
    for (int t = 1; t < 5; ++t)
        if (parity14((unsigned)(vec & P.rows[t]))) r = (unsigned short)(r ^ P.tmask[t]);
    return r;
}

// ---- lane/wave vectors: lane[0] forced = tmask[0] (lane-bit direction in wave span) ----
struct VecsT { unsigned short lane[NP][6]; unsigned short g[NP/2][4]; int ok; };
constexpr VecsT build_vecs() {
    VecsT V{}; V.ok = 1;
    for (int k = 0; k < NP/2; ++k) {
        const PassD& P0 = A.pass[2*k];
        const PassD& P1 = A.pass[2*k + 1];
        Span SW{}; unsigned short Wb[10] = {}; int nw = 0;
        for (int i = 0; i < 5; ++i) if (SW.add(P0.tmask[i])) Wb[nw++] = P0.tmask[i];
        for (int i = 0; i < 5; ++i) if (nw < 10 && SW.add(P1.tmask[i])) Wb[nw++] = P1.tmask[i];
        for (int b = 0; b < 14 && nw < 10; ++b) {
            unsigned short e = (unsigned short)(1u << b);
            if (SW.add(e)) Wb[nw++] = e;
        }
        if (nw != 10) V.ok = 0;
        Span SG = SW; int ngv = 0;
        for (int b = 0; b < 14 && ngv < 4; ++b) {
            unsigned short e = (unsigned short)(1u << b);
            if (SG.add(e)) V.g[k][ngv++] = e;
        }
        if (ngv != 4) V.ok = 0;
        for (int pp = 0; pp < 2; ++pp) {
            const PassD& P = (pp == 0) ? P0 : P1;
            int pidx = 2*k + pp;
            Span ST{};
            for (int i = 1; i < 5; ++i) ST.add(P.tmask[i]);   // local span
            int nl = 0;
            if (ST.add(P.tmask[0])) V.lane[pidx][nl++] = P.tmask[0];
            else V.ok = 0;
            for (int i = 0; i < 10 && nl < 6; ++i)
                if (ST.add(Wb[i])) V.lane[pidx][nl++] = Wb[i];
            if (nl != 6) V.ok = 0;
            Span SF{};
            for (int i = 1; i < 5; ++i) SF.add(P.tmask[i]);
            for (int i = 0; i < 6; ++i) if (!SF.add(V.lane[pidx][i])) V.ok = 0;
            for (int i = 0; i < 4; ++i) if (!SF.add(V.g[k][i])) V.ok = 0;
            if (SF.n != 14) V.ok = 0;
        }
    }
    return V;
}
constexpr VecsT VC = build_vecs();
static_assert(VC.ok == 1, "vec construction failed");

struct P6T { unsigned short u[NP][6]; };
constexpr P6T build_p6() {
    P6T X{};
    for (int p = 0; p < NP; ++p)
        for (int i = 0; i < 6; ++i)
            X.u[p][i] = proj(VC.lane[p][i], A.pass[p]);
    return X;
}
constexpr P6T P6 = build_p6();

// ---- bank map L' : F2^14 -> F2^4 ----
constexpr unsigned lmap(const unsigned short* row, unsigned x) {
    unsigned l = 0;
    for (int t = 0; t < 4; ++t) l |= (unsigned)parity14(row[t] & x) << t;
    return l;
}
constexpr int nib_rank(const unsigned* nibs, int n) {
    unsigned basis[4] = {};
    int r = 0;
    for (int i = 0; i < n; ++i) {
        unsigned v = nibs[i] & 15u;
        for (int b = 3; b >= 0 && v; --b) {
            if (!((v >> b) & 1)) continue;
            if (basis[b]) v ^= basis[b];
            else { basis[b] = v; ++r; v = 0; }
        }
    }
    return r;
}
struct Lp { unsigned short row[4]; int score; };

constexpr int full_score(const unsigned short* r) {
    unsigned cn[4] = {};
    for (int c = 0; c < 4; ++c) {
        unsigned v = 0;
        for (int t = 0; t < 4; ++t) v |= ((unsigned)(r[t] >> c) & 1u) << t;
        cn[c] = v;
    }
    if (nib_rank(cn, 4) != 4) return -1;
    int sc = 0;
    for (int p = 0; p < NP; ++p) {
        unsigned im[6] = {};
        for (int i = 0; i < 6; ++i) im[i] = lmap(r, P6.u[p][i]);
        if (nib_rank(im, 6) == 4) ++sc;
    }
    return sc;
}

constexpr Lp search_stage(unsigned seed, int iters) {
    Lp best{}; best.score = -1;
    unsigned s = seed;
    for (int it = 0; it < iters; ++it) {
        unsigned short r[4] = {};
        for (int t = 0; t < 4; ++t) { s = s*1664525u + 1013904223u; r[t] = (unsigned short)((s >> 9) & 0x3FFF); }
        int sc = full_score(r);
        if (sc > best.score) { best.score = sc; for (int t = 0; t < 4; ++t) best.row[t] = r[t]; }
        if (best.score == NP) break;
    }
    return best;
}
constexpr Lp S0 = search_stage(0x12345u, 400);
constexpr Lp S1 = search_stage(0xBEEF1u, 400);
constexpr Lp S2 = search_stage(0xC0FFEu, 400);
constexpr Lp S3 = search_stage(0x777A1u, 400);
constexpr Lp S4 = search_stage(0x51DE5u, 400);
constexpr Lp S5 = search_stage(0xA11CEu, 400);
constexpr Lp S6 = search_stage(0x0F00Du, 400);
constexpr Lp S7 = search_stage(0x13579u, 400);
constexpr Lp pick_best() {
    Lp b = S0;
    if (S1.score > b.score) b = S1;
    if (S2.score > b.score) b = S2;
    if (S3.score > b.score) b = S3;
    if (S4.score > b.score) b = S4;
    if (S5.score > b.score) b = S5;
    if (S6.score > b.score) b = S6;
    if (S7.score > b.score) b = S7;
    return b;
}
constexpr Lp climb(Lp start, int sweeps) {
    Lp cur = start;
    for (int sw = 0; sw < sweeps && cur.score < NP; ++sw) {
        for (int t = 0; t < 4; ++t) {
            for (int b = 0; b < 14; ++b) {
                if (cur.score >= NP) break;
                unsigned short nr[4] = {cur.row[0], cur.row[1], cur.row[2], cur.row[3]};
                nr[t] = (unsigned short)(nr[t] ^ (1u << b));
                int sc = full_score(nr);
                if (sc > cur.score) { cur.score = sc; cur.row[t] = nr[t]; }
            }
        }
    }
    return cur;
}
constexpr Lp C0 = climb(pick_best(), 2);
constexpr Lp C1 = climb(C0, 2);
constexpr Lp LSEL = C1;
static_assert(LSEL.score >= 13, "bank-map search failed badly");

constexpr unsigned short swz2(unsigned short x) {
    return (unsigned short)(((unsigned)x & ~15u) | lmap(LSEL.row, x));
}

// ---- lane-basis canonicalization: slot-map kernel -> lane bits 4,5 ----
constexpr int add_basis4(unsigned* basis, unsigned v) {
    for (int b = 3; b >= 0; --b) {
        if (!((v >> b) & 1)) continue;
        if (basis[b]) v ^= basis[b];
        else { basis[b] = v; return 1; }
    }
    return 0;
}
constexpr int add_basis6(unsigned* basis, unsigned v) {
    for (int b = 5; b >= 0; --b) {
        if (!((v >> b) & 1)) continue;
        if (basis[b]) v ^= basis[b];
        else { basis[b] = v; return 1; }
    }
    return 0;
}
struct LaneOrd { unsigned short lane[NP][6]; };
constexpr LaneOrd build_lane2() {
    LaneOrd O{};
    for (int p = 0; p < NP; ++p) {
        for (int i = 0; i < 6; ++i) O.lane[p][i] = VC.lane[p][i];
        unsigned imu[6] = {};
        for (int i = 0; i < 6; ++i) imu[i] = lmap(LSEL.row, P6.u[p][i]);
        {
            unsigned chk[6] = {imu[0], imu[1], imu[2], imu[3], imu[4], imu[5]};
            if (nib_rank(chk, 6) != 4) continue;   // fallback: keep default order
        }
        unsigned short nl[6] = {};
        int ns = 0;
        unsigned ib[4] = {};
        unsigned sb[6] = {};
        for (unsigned c = 1; c < 64 && ns < 4; ++c) {
            unsigned img = 0; unsigned short rv = 0;
            for (int i = 0; i < 6; ++i) if ((c >> i) & 1) { img ^= imu[i]; rv = (unsigned short)(rv ^ VC.lane[p][i]); }
            if (img == 0) continue;
            unsigned ib2[4] = {ib[0], ib[1], ib[2], ib[3]};
            unsigned sb2[6] = {sb[0], sb[1], sb[2], sb[3], sb[4], sb[5]};
            if (add_basis4(ib2, img) && add_basis6(sb2, c)) {
                for (int t = 0; t < 4; ++t) ib[t] = ib2[t];
                for (int t = 0; t < 6; ++t) sb[t] = sb2[t];
                nl[ns++] = rv;
            }
        }
        for (unsigned c = 1; c < 64 && ns < 6; ++c) {
            unsigned img = 0; unsigned short rv = 0;
            for (int i = 0; i < 6; ++i) if ((c >> i) & 1) { img ^= imu[i]; rv = (unsigned short)(rv ^ VC.lane[p][i]); }
            if (img != 0) continue;
            unsigned sb2[6] = {sb[0], sb[1], sb[2], sb[3], sb[4], sb[5]};
            if (add_basis6(sb2, c)) {
                for (int t = 0; t < 6; ++t) sb[t] = sb2[t];
                nl[ns++] = rv;
            }
        }
        if (ns == 6)
            for (int i = 0; i < 6; ++i) O.lane[p][i] = nl[i];
    }
    return O;
}
constexpr LaneOrd LO = build_lane2();

// ---- shuffle masks for the 3 shuffle-RY gates: combo of FINAL lane basis == tmask[0] ----
struct SHMt { int m[NP]; int ok; };
constexpr SHMt build_shm() {
    SHMt S{}; S.ok = 1;
    for (int p = 0; p < NP; ++p) {
        S.m[p] = 0;
        if (!A.pass[p].has_shry) continue;
        int found = 0;
        for (unsigned c = 1; c < 64 && !found; ++c) {
            unsigned short x = 0;
            for (int i = 0; i < 6; ++i) if ((c >> i) & 1) x = (unsigned short)(x ^ LO.lane[p][i]);
            if (x == A.pass[p].tmask[0]) { S.m[p] = (int)c; found = 1; }
        }
        if (!found) S.ok = 0;
    }
    return S;
}
constexpr SHMt SHM = build_shm();
static_assert(SHM.ok == 1, "shuffle mask not found");

// pre-swizzled combo offsets
struct CS2 { unsigned short c[NP][NE]; };
constexpr CS2 build_cs2() {
    CS2 C{};
    for (int p = 0; p < NP; ++p)
        for (int j = 0; j < NE; ++j)
            C.c[p][j] = swz2(A.pass[p].comboR[j]);
    return C;
}
constexpr CS2 CSS = build_cs2();

struct LJt { unsigned short v[NE]; };
constexpr LJt build_lj() {
    LJt t{};
    for (int j = 0; j < NE; ++j) t.v[j] = (unsigned short)lmap(LSEL.row, (unsigned)(j * THREADS));
    return t;
}
constexpr LJt LJ = build_lj();

// entry = (swz2(proj(vec))<<3) | (par << 22); par bits 0-8 = ng parities, bit 9 = s4 (lane side)
constexpr unsigned pack_entry(unsigned short vec0, int p) {
    const PassD& P = A.pass[p];
    unsigned short vec = proj(vec0, P);
    unsigned par = 0;
    if (P.rzidx >= 0)
        for (int t = 0; t < 9; ++t) par |= (unsigned)parity14(vec & A.rz[P.rzidx].rows_ng[t]) << t;
    if (P.measfold)
        for (int t = 0; t < 9; ++t) par |= (unsigned)parity14(vec & A.meas_rows_ng[t]) << t;
    par |= (unsigned)parity14(vec & P.rows[0]) << 9;
    return ((unsigned)swz2(vec) << 3) | (par << 22);
}

// LUT0: tid bits 0-4 (lanes 0-4); LUT1: tid bits 5-9 (lane 5 + wave g[0..3])
struct LutsT { unsigned v[NP][2][32]; };
constexpr LutsT build_luts() {
    LutsT L{};
    for (int p = 0; p < NP; ++p) {
        int k = p >> 1;
        for (int t = 0; t < 32; ++t) {
            unsigned short x = 0;
            for (int i = 0; i < 5; ++i) if ((t >> i) & 1) x = (unsigned short)(x ^ LO.lane[p][i]);
            L.v[p][0][t] = pack_entry(x, p);
            unsigned short y = 0;
            if (t & 1) y = (unsigned short)(y ^ LO.lane[p][5]);
            for (int i = 0; i < 4; ++i) if ((t >> (i + 1)) & 1) y = (unsigned short)(y ^ VC.g[k][i]);
            L.v[p][1][t] = pack_entry(y, p);
        }
    }
    return L;
}
constexpr LutsT LUTS = build_luts();
__device__ __constant__ LutsT cLUTS = LUTS;

// ---------------- per-pass device code ----------------
template<int Pi>
__device__ __forceinline__ void run_pass(f2* st, const f2 (*tabG)[8], const float (*tabRZ)[14],
                                         unsigned comb, float* acc)
{
    constexpr PassD Pd = A.pass[Pi];
    char* stb = (char*)st;
    const int base = (int)(comb & 0x1FFF8u);
    const unsigned par = comb >> 22;          // 9 ng bits + s4 at bit 9

    f2 v[NE];
#pragma unroll
    for (int j = 0; j < NE; ++j)
        v[j] = *(const f2*)(stb + (base ^ (CSS.c[Pi][j] << 3)));

    // ---- fused RZ layer (pass 0 of each block) ----
    if constexpr (Pd.rzidx >= 0) {
        float phi0 = 0.f;
#pragma unroll
        for (int t = 0; t < 9; ++t) {
            float h = tabRZ[Pd.rzidx][t];
            phi0 += ((par >> t) & 1) ? h : -h;
        }
        { float h = tabRZ[Pd.rzidx][13]; phi0 += ((par >> 9) & 1) ? h : -h; }  // lane-bit group term
        const float h0 = tabRZ[Pd.rzidx][9],  h1 = tabRZ[Pd.rzidx][10];
        const float h2 = tabRZ[Pd.rzidx][11], h3 = tabRZ[Pd.rzidx][12];
#pragma unroll
        for (int j = 0; j < NE; ++j) {
            float phi = ((((phi0 + ((j & 1) ? h0 : -h0)) + ((j & 2) ? h1 : -h1))
                                 + ((j & 4) ? h2 : -h2)) + ((j & 8) ? h3 : -h3));
            float s, c; __sincosf(phi, &s, &c);
            f2 C = {c, c}, S = {-s, s};
            v[j] = C * v[j] + S * v[j].yx;
        }
    }

    // ---- gate 0: control = LANE bit (thread-side s4) -> pure predication, no exchange ----
    if constexpr (Pd.has_g0) {
        f2 cs = tabG[Pi][0];
        int s4v = (int)((par >> 9) & 1);
        float ce = s4v ? cs.x : 1.f, se = s4v ? cs.y : 0.f;
        f2 C = {ce, ce}, S = {se, -se};
#pragma unroll
        for (int j = 0; j < NE; ++j) if (!(j & 1)) {
            int j1 = j | 1;
            f2 a0 = v[j], a1 = v[j1];
            v[j]  = C * a0 + S * a1.yx;
            v[j1] = C * a1 + S * a0.yx;
        }
    }

    // ---- local chain gates: ctrl local bit lg, tgt local bit lg+1 (canonical: 4 pairs) ----
#pragma unroll
    for (int lg = 0; lg < Pd.ngl; ++lg) {
        f2 cs = tabG[Pi][1 + lg];
        f2 C = {cs.x, cs.x}, S = {cs.y, -cs.y};
#pragma unroll
        for (int j = 0; j < NE; ++j) if (((j >> lg) & 1) && !((j >> (lg + 1)) & 1)) {
            int j1 = j | (1 << (lg + 1));
            f2 a0 = v[j], a1 = v[j1];
            v[j]  = C * a0 + S * a1.yx;
            v[j1] = C * a1 + S * a0.yx;
        }
    }

    // ---- folded next-block RY gates (local) ----
#pragma unroll
    for (int g = 0; g < Pd.nry; ++g) {
        int t = Pd.ry_tb[g];
        f2 cs = tabG[Pi][4 + g];
        f2 C = {cs.x, cs.x}, Sv = {cs.y, cs.y}, NS = {-cs.y, -cs.y};
#pragma unroll
        for (int j = 0; j < NE; ++j) if (!((j >> t) & 1)) {
            int j1 = j | (1 << t);
            f2 a0 = v[j], a1 = v[j1];
            v[j]  = C * a0 + NS * a1;
            v[j1] = Sv * a0 + C * a1;
        }
    }

    // ---- shuffle-RY on the lane bit (1 per block transition; 3 total) ----
    if constexpr (Pd.has_shry) {
        constexpr int sm = SHM.m[Pi];
        f2 cs = tabG[Pi][3];
        int s4v = (int)((par >> 9) & 1);
        // RY: side0' = c*v0 - s*v1 ; side1' = s*v0 + c*v1  ->  v' = c*own + (side? +s : -s)*partner
        float se = s4v ? cs.y : -cs.y;
        f2 C = {cs.x, cs.x}, S = {se, se};
#pragma unroll
        for (int j = 0; j < NE; ++j) {
            f2 pv;
            pv.x = __shfl_xor(v[j].x, sm, 64);
            pv.y = __shfl_xor(v[j].y, sm, 64);
            v[j] = C * v[j] + S * pv;
        }
    }

    if constexpr (Pd.measfold != 0) {
        f2 ps = {0.f, 0.f}, p0 = {0.f, 0.f}, p1 = {0.f, 0.f}, p2 = {0.f, 0.f}, p3 = {0.f, 0.f};
#pragma unroll
        for (int j = 0; j < NE; ++j) {
            f2 t2 = v[j] * v[j];
            ps += t2;
            if (j & 1) p0 += t2;
            if (j & 2) p1 += t2;
            if (j & 4) p2 += t2;
            if (j & 8) p3 += t2;
        }
        float psum = ps.x + ps.y;
        float pg0 = p0.x + p0.y, pg1 = p1.x + p1.y, pg2 = p2.x + p2.y, pg3 = p3.x + p3.y;
        // locals: L0=bit1->q12, L1=bit0->q13, L2=bit13->q0, L3=bit5->q8 (canonical +1 signs)
        acc[12] += psum - 2.f * pg0;
        acc[13] += psum - 2.f * pg1;
        acc[0]  += psum - 2.f * pg2;
        acc[8]  += psum - 2.f * pg3;
        // lane bit 9 -> qubit 4: sign from s4
        float s4 = ((par >> 9) & 1) ? -1.f : 1.f;
        acc[4] += s4 * psum;
        constexpr int MQ[9] = {1,2,3,5,6,7,9,10,11};
#pragma unroll
        for (int t = 0; t < 9; ++t) {
            float sg = ((par >> t) & 1) ? -1.f : 1.f;
            acc[MQ[t]] += sg * psum;
        }
    } else {
#pragma unroll
        for (int j = 0; j < NE; ++j)
            *(f2*)(stb + (base ^ (CSS.c[Pi][j] << 3))) = v[j];
        // wave-closed pairing: barrier only at end of each (even,odd) pair.
        if constexpr ((Pi & 1) != 0) __syncthreads();
    }
}

template<int... I>
__device__ __forceinline__ void run_all(std::integer_sequence<int, I...>,
                                        f2* st, const f2 (*tabG)[8], const float (*tabRZ)[14],
                                        const unsigned* comb, float* acc)
{
    (run_pass<I>(st, tabG, tabRZ, comb[I], acc), ...);
}

// ---------------- main kernel ----------------
// 1024 threads (16 waves, 4/SIMD); LDS caps 1 block/CU -> VGPR cap 128.
__global__ __launch_bounds__(THREADS, 4)
void qsim_kernel(const float* __restrict__ inputs,
                 const float* __restrict__ weights,
                 float* __restrict__ out)
{
    __shared__ f2     st[NST];           // 128 KiB state
    __shared__ float  tab[256];
    __shared__ f2     tabG[NP][8];
    __shared__ float  tabRZ[4][14];      // [0..8] ng, [9..12] local group, [13] lane group
    __shared__ float  red[THREADS / 64][NQ];

    const int b = blockIdx.x;
    const int tid = threadIdx.x;

    unsigned comb[NP];
#pragma unroll
    for (int p = 0; p < NP; ++p)
        comb[p] = cLUTS.v[p][0][tid & 31] ^ cLUTS.v[p][1][tid >> 5];

    // ---- build trig + product tables (disjoint thread ranges) ----
    if (tid < 128) {
        int p = tid >> 3, sl = tid & 7;
        float w = weights[GW.w[p][sl]];
        float s, c; __sincosf(0.5f * w, &s, &c);
        tabG[p][sl] = (f2){c, s};
    } else if (tid >= 128 && tid < 128 + 56) {
        int idx = tid - 128;
        int blk = idx / 14, k = idx - blk * 14;
        unsigned wi = (k < 9) ? A.rz[blk].widx_ng[k] : A.rz[blk].widx_g[k - 9];
        tabRZ[blk][k] = 0.5f * weights[wi];
    } else if (tid >= 256 && tid < 512) {
        int t = tid - 256;
        int half = t >> 7, tt = t & 127;
        float prod = 1.f;
#pragma unroll
        for (int j = 0; j < 7; ++j) {
            int xb = j + 7 * half;
            int q  = 13 - xb;
            float a = 0.5f * (inputs[b * NQ + q] + weights[q]);   // init RY ∘ blk0 RY fold
            float s, c; __sincosf(a, &s, &c);
            prod *= ((tt >> j) & 1) ? s : c;
        }
        tab[t] = prod;
    }
    __syncthreads();

    // ---- write product state with swz2 ----
    unsigned l4t = 0;
#pragma unroll
    for (int t = 0; t < 4; ++t)
        l4t |= (unsigned)(__popc((int)(LSEL.row[t] & tid)) & 1) << t;
#pragma unroll
    for (int j = 0; j < NE; ++j) {
        int x = tid + j * THREADS;
        int addr = (x & ~15) | (int)(l4t ^ LJ.v[j]);
        st[addr] = (f2){tab[x & 127] * tab[128 + (x >> 7)], 0.f};
    }
    __syncthreads();

    float acc[NQ];
#pragma unroll
    for (int q = 0; q < NQ; ++q) acc[q] = 0.f;

    run_all(std::make_integer_sequence<int, NP>{}, st, tabG, tabRZ, comb, acc);

    // ---- block-wide reduction ----
#pragma unroll
    for (int q = 0; q < NQ; ++q) {
        float v2 = acc[q];
        v2 += __shfl_down(v2, 32);
        v2 += __shfl_down(v2, 16);
        v2 += __shfl_down(v2, 8);
        v2 += __shfl_down(v2, 4);
        v2 += __shfl_down(v2, 2);
        v2 += __shfl_down(v2, 1);
        acc[q] = v2;
    }
    const int wave = tid >> 6, lane = tid & 63;
    if (lane == 0) {
#pragma unroll
        for (int q = 0; q < NQ; ++q) red[wave][q] = acc[q];
    }
    __syncthreads();
    if (tid < NQ) {
        float v2 = 0.f;
#pragma unroll
        for (int w = 0; w < THREADS / 64; ++w) v2 += red[w][tid];
        out[b * NQ + tid] = v2;
    }
}

extern "C" void kernel_launch(void* const* d_in, const int* in_sizes, int n_in,
                              void* d_out, int out_size, void* d_ws, size_t ws_size,
                              hipStream_t stream) {
    const float* inputs  = (const float*)d_in[0];
    const float* weights = (const float*)d_in[1];
    float* out = (float*)d_out;
    const int B = in_sizes[0] / NQ;   // 256
    qsim_kernel<<<dim3(B), dim3(THREADS), 0, stream>>>(inputs, weights, out);
}

// Round 14
// 43.037 us; speedup vs baseline: 1.1125x; 1.0371x over previous
//
#include <hip/hip_runtime.h>
#include <utility>

#define NQ 14
#define NST (1 << NQ)      // 16384
#define THREADS 512
#define NP 16              // passes
#define NE 32              // elements per thread (5-bit tile)

typedef float f2 __attribute__((ext_vector_type(2)));

// ---------------- compile-time schedule (5-bit tiles, 4 passes/block) ----------------
struct PassD {
    unsigned short comboR[NE];  // RAW xor offsets (element units, unswizzled)
    unsigned short rows[5];     // R row (base-parity mask) per tile bit
    unsigned short tmask[5];    // C column (tile span mask) per tile bit
    unsigned short crx_widx[4];
    unsigned short ry_widx[4];
    unsigned char  ry_tb[4];
    unsigned char  ncrx;        // 2 or 4
    unsigned char  nry;         // 0..4
    short          rzidx;
    unsigned char  measfold;
};
struct RZD  { unsigned short rows_ng[9]; unsigned short widx_ng[9]; unsigned short widx_g[5]; };
struct AllD { PassD pass[NP]; RZD rz[4]; unsigned short meas_rows_ng[9]; int npass; };

constexpr void fill_geom(PassD& P, const unsigned short* R, const unsigned short* C, const int* tb)
{
    for (int i = 0; i < 5; ++i) { P.tmask[i] = C[tb[i]]; P.rows[i] = R[tb[i]]; }
    for (int j = 0; j < NE; ++j) {
        unsigned short x = 0;
        for (int i = 0; i < 5; ++i) if ((j >> i) & 1) x = (unsigned short)(x ^ P.tmask[i]);
        P.comboR[j] = x;
    }
}

constexpr void ring(unsigned short* R, unsigned short* C) {
    for (int q = 0; q < NQ; ++q) {
        int cb = 13 - q, tb = 13 - ((q + 1) % NQ);
        R[tb] = (unsigned short)(R[tb] ^ R[cb]);
        C[cb] = (unsigned short)(C[cb] ^ C[tb]);
    }
}

constexpr AllD build_desc() {
    AllD A{};
    unsigned short R[NQ] = {}, C[NQ] = {};
    for (int k = 0; k < NQ; ++k) { R[k] = (unsigned short)(1u << k); C[k] = (unsigned short)(1u << k); }
    int np = 0;
    // 4 passes per block; chain gate g: control tile-bit g, target tile-bit g+1.
    const int tiles[4][5]  = {{13,12,11,10,9},{9,8,7,6,5},{5,4,3,2,1},{1,0,13,3,2}};
    const int gfirst[4]    = {0, 4, 8, 12};
    const int ngate[4]     = {4, 4, 4, 2};
    const int rybits[4][4] = {{12,11,10,0},{9,8,7,6},{5,4,3,2},{13,1,0,0}};
    const int nryp[4]      = {3, 4, 4, 3};

    for (int blk = 0; blk < 4; ++blk) {
        ring(R, C);   // CNOT ring = pure relabeling
        for (int pi = 0; pi < 4; ++pi) {
            PassD& P = A.pass[np];
            fill_geom(P, R, C, tiles[pi]);
            P.ncrx = (unsigned char)ngate[pi];
            for (int g = 0; g < 4; ++g)
                P.crx_widx[g] = (unsigned short)((g < ngate[pi]) ? blk*42 + 28 + gfirst[pi] + g : 0);
            if (blk < 3) {
                P.nry = (unsigned char)nryp[pi];
                for (int g = 0; g < 4; ++g) {
                    if (g < nryp[pi]) {
                        int k = rybits[pi][g];
                        P.ry_widx[g] = (unsigned short)((blk + 1)*42 + (13 - k));
                        int t = 0;
                        for (int i = 0; i < 5; ++i) if (tiles[pi][i] == k) t = i;
                        P.ry_tb[g] = (unsigned char)t;
                    } else { P.ry_widx[g] = 0; P.ry_tb[g] = 0; }
                }
            } else { P.nry = 0; for (int g = 0; g < 4; ++g) { P.ry_widx[g] = 0; P.ry_tb[g] = 0; } }
            P.rzidx = (short)((pi == 0) ? blk : -1);
            P.measfold = (unsigned char)((blk == 3 && pi == 3) ? 1 : 0);
            if (pi == 0) {
                RZD& Z = A.rz[blk];
                for (int i = 0; i < 5; ++i)
                    Z.widx_g[i] = (unsigned short)(blk*42 + 14 + (13 - tiles[0][i]));
                // non-group qubits 5..13 (state bits 8..0)
                int t = 0;
                for (int q = 5; q < NQ; ++q, ++t) {
                    Z.rows_ng[t] = R[13 - q];
                    Z.widx_ng[t] = (unsigned short)(blk*42 + 14 + q);
                }
            }
            ++np;
        }
        if (blk == 3)
            for (int t = 0; t < 9; ++t) A.meas_rows_ng[t] = R[13 - (1 + t)];  // qubits 1..9
    }
    A.npass = np;
    return A;
}

constexpr AllD A = build_desc();
static_assert(A.npass == NP, "expected 16 passes");

constexpr int parity14(unsigned v) { v ^= v >> 8; v ^= v >> 4; v ^= v >> 2; v ^= v >> 1; return (int)(v & 1); }

constexpr bool check_dual() {
    for (int p = 0; p < NP; ++p)
        for (int i = 0; i < 5; ++i)
            for (int j = 0; j < 5; ++j)
                if (parity14((unsigned)(A.pass[p].rows[i] & A.pass[p].tmask[j])) != (i == j ? 1 : 0))
                    return false;
    return true;
}
static_assert(check_dual(), "R/C duality violated");

// flat gate-weight-index table (slots 0-3 CRX, 4-7 RY)
struct GWT { unsigned short w[NP][8]; };
constexpr GWT build_gwt() {
    GWT g{};
    for (int p = 0; p < NP; ++p) {
        for (int s = 0; s < 4; ++s) g.w[p][s]     = A.pass[p].crx_widx[s];
        for (int s = 0; s < 4; ++s) g.w[p][4 + s] = A.pass[p].ry_widx[s];
    }
    return g;
}
constexpr GWT GW = build_gwt();

// ---------------- GF(2) machinery ----------------
constexpr int lead(unsigned short v) { int b = 13; while (b > 0 && !((v >> b) & 1)) --b; return b; }

struct Span {
    unsigned short red[14]; int n;
    constexpr unsigned short reduce(unsigned short v) const {
        for (int i = 0; i < n; ++i) { int lb = lead(red[i]); if ((v >> lb) & 1) v = (unsigned short)(v ^ red[i]); }
        return v;
    }
    constexpr bool add(unsigned short v) {
        unsigned short r = reduce(v);
        if (!r) return false;
        red[n++] = r; return true;
    }
};

// M-projection: canonical coset representative (zeros all 5 tile parities).
constexpr unsigned short proj(unsigned short vec, const PassD& P) {
    unsigned short r = vec;
    for (int t = 0; t < 5; ++t)
        if (parity14((unsigned)(vec & P.rows[t]))) r = (unsigned short)(r ^ P.tmask[t]);
    return r;
}

// ---- lane/wave vector construction (wave-closed pairing; tile5 + lane6 = 11 >= dim(W)) ----
struct VecsT { unsigned short lane[NP][6]; unsigned short g[NP/2][3]; int ok; };
constexpr VecsT build_vecs() {
    VecsT V{}; V.ok = 1;
    for (int k = 0; k < NP/2; ++k) {
        const PassD& P0 = A.pass[2*k];
        const PassD& P1 = A.pass[2*k + 1];
        Span SW{}; unsigned short Wb[11] = {}; int nw = 0;
        for (int i = 0; i < 5; ++i) if (SW.add(P0.tmask[i])) Wb[nw++] = P0.tmask[i];
        for (int i = 0; i < 5; ++i) if (nw < 11 && SW.add(P1.tmask[i])) Wb[nw++] = P1.tmask[i];
        for (int b = 0; b < 14 && nw < 11; ++b) {
            unsigned short e = (unsigned short)(1u << b);
            if (SW.add(e)) Wb[nw++] = e;
        }
        if (nw != 11) V.ok = 0;
        Span SG = SW; int ngv = 0;
        for (int b = 0; b < 14 && ngv < 3; ++b) {
            unsigned short e = (unsigned short)(1u << b);
            if (SG.add(e)) V.g[k][ngv++] = e;
        }
        if (ngv != 3) V.ok = 0;
        for (int pp = 0; pp < 2; ++pp) {
            const PassD& P = (pp == 0) ? P0 : P1;
            int pidx = 2*k + pp;
            Span ST{};
            for (int i = 0; i < 5; ++i) ST.add(P.tmask[i]);
            int nl = 0;
            for (int i = 0; i < 11 && nl < 6; ++i)
                if (ST.add(Wb[i])) V.lane[pidx][nl++] = Wb[i];
            if (nl != 6) V.ok = 0;
            Span SF{};
            for (int i = 0; i < 5; ++i) SF.add(P.tmask[i]);
            for (int i = 0; i < 6; ++i) if (!SF.add(V.lane[pidx][i])) V.ok = 0;
            for (int i = 0; i < 3; ++i) if (!SF.add(V.g[k][i])) V.ok = 0;
            if (SF.n != 14) V.ok = 0;
        }
    }
    return V;
}
constexpr VecsT VC = build_vecs();
static_assert(VC.ok == 1, "vec construction failed");

struct P6T { unsigned short u[NP][6]; };
constexpr P6T build_p6() {
    P6T X{};
    for (int p = 0; p < NP; ++p)
        for (int i = 0; i < 6; ++i)
            X.u[p][i] = proj(VC.lane[p][i], A.pass[p]);
    return X;
}
constexpr P6T P6 = build_p6();

// ---- bank map L' : F2^14 -> F2^4 ----
constexpr unsigned lmap(const unsigned short* row, unsigned x) {
    unsigned l = 0;
    for (int t = 0; t < 4; ++t) l |= (unsigned)parity14(row[t] & x) << t;
    return l;
}
constexpr int nib_rank(const unsigned* nibs, int n) {
    unsigned basis[4] = {};
    int r = 0;
    for (int i = 0; i < n; ++i) {
        unsigned v = nibs[i] & 15u;
        for (int b = 3; b >= 0 && v; --b) {
            if (!((v >> b) & 1)) continue;
            if (basis[b]) v ^= basis[b];
            else { basis[b] = v; ++r; v = 0; }
        }
    }
    return r;
}
struct Lp { unsigned short row[4]; int score; };

constexpr int full_score(const unsigned short* r) {
    unsigned cn[4] = {};
    for (int c = 0; c < 4; ++c) {
        unsigned v = 0;
        for (int t = 0; t < 4; ++t) v |= ((unsigned)(r[t] >> c) & 1u) << t;
        cn[c] = v;
    }
    if (nib_rank(cn, 4) != 4) return -1;
    int sc = 0;
    for (int p = 0; p < NP; ++p) {
        unsigned im[6] = {};
        for (int i = 0; i < 6; ++i) im[i] = lmap(r, P6.u[p][i]);
        if (nib_rank(im, 6) == 4) ++sc;
    }
    return sc;
}

constexpr Lp search_stage(unsigned seed, int iters) {
    Lp best{}; best.score = -1;
    unsigned s = seed;
    for (int it = 0; it < iters; ++it) {
        unsigned short r[4] = {};
        for (int t = 0; t < 4; ++t) { s = s*1664525u + 1013904223u; r[t] = (unsigned short)((s >> 9) & 0x3FFF); }
        int sc = full_score(r);
        if (sc > best.score) { best.score = sc; for (int t = 0; t < 4; ++t) best.row[t] = r[t]; }
        if (best.score == NP) break;
    }
    return best;
}
constexpr Lp S0 = search_stage(0x12345u, 400);
constexpr Lp S1 = search_stage(0xBEEF1u, 400);
constexpr Lp S2 = search_stage(0xC0FFEu, 400);
constexpr Lp S3 = search_stage(0x777A1u, 400);
constexpr Lp S4 = search_stage(0x51DE5u, 400);
constexpr Lp S5 = search_stage(0xA11CEu, 400);
constexpr Lp S6 = search_stage(0x0F00Du, 400);
constexpr Lp S7 = search_stage(0x13579u, 400);
constexpr Lp pick_best() {
    Lp b = S0;
    if (S1.score > b.score) b = S1;
    if (S2.score > b.score) b = S2;
    if (S3.score > b.score) b = S3;
    if (S4.score > b.score) b = S4;
    if (S5.score > b.score) b = S5;
    if (S6.score > b.score) b = S6;
    if (S7.score > b.score) b = S7;
    return b;
}
constexpr Lp climb(Lp start, int sweeps) {
    Lp cur = start;
    for (int sw = 0; sw < sweeps && cur.score < NP; ++sw) {
        for (int t = 0; t < 4; ++t) {
            for (int b = 0; b < 14; ++b) {
                if (cur.score >= NP) break;
                unsigned short nr[4] = {cur.row[0], cur.row[1], cur.row[2], cur.row[3]};
                nr[t] = (unsigned short)(nr[t] ^ (1u << b));
                int sc = full_score(nr);
                if (sc > cur.score) { cur.score = sc; cur.row[t] = nr[t]; }
            }
        }
    }
    return cur;
}
constexpr Lp C0 = climb(pick_best(), 2);
constexpr Lp C1 = climb(C0, 2);
constexpr Lp LSEL = C1;
static_assert(LSEL.score >= 13, "bank-map search failed badly");

constexpr unsigned short swz2(unsigned short x) {
    return (unsigned short)(((unsigned)x & ~15u) | lmap(LSEL.row, x));
}

// ---- lane-basis canonicalization: slot-map kernel -> lane bits 4,5 ----
constexpr int add_basis4(unsigned* basis, unsigned v) {
    for (int b = 3; b >= 0; --b) {
        if (!((v >> b) & 1)) continue;
        if (basis[b]) v ^= basis[b];
        else { basis[b] = v; return 1; }
    }
    return 0;
}
constexpr int add_basis6(unsigned* basis, unsigned v) {
    for (int b = 5; b >= 0; --b) {
        if (!((v >> b) & 1)) continue;
        if (basis[b]) v ^= basis[b];
        else { basis[b] = v; return 1; }
    }
    return 0;
}
struct LaneOrd { unsigned short lane[NP][6]; };
constexpr LaneOrd build_lane2() {
    LaneOrd O{};
    for (int p = 0; p < NP; ++p) {
        for (int i = 0; i < 6; ++i) O.lane[p][i] = VC.lane[p][i];
        unsigned imu[6] = {};
        for (int i = 0; i < 6; ++i) imu[i] = lmap(LSEL.row, P6.u[p][i]);
        {
            unsigned chk[6] = {imu[0], imu[1], imu[2], imu[3], imu[4], imu[5]};
            if (nib_rank(chk, 6) != 4) continue;   // fallback: keep default order
        }
        unsigned short nl[6] = {};
        int ns = 0;
        unsigned ib[4] = {};
        unsigned sb[6] = {};
        for (unsigned c = 1; c < 64 && ns < 4; ++c) {
            unsigned img = 0; unsigned short rv = 0;
            for (int i = 0; i < 6; ++i) if ((c >> i) & 1) { img ^= imu[i]; rv = (unsigned short)(rv ^ VC.lane[p][i]); }
            if (img == 0) continue;
            unsigned ib2[4] = {ib[0], ib[1], ib[2], ib[3]};
            unsigned sb2[6] = {sb[0], sb[1], sb[2], sb[3], sb[4], sb[5]};
            if (add_basis4(ib2, img) && add_basis6(sb2, c)) {
                for (int t = 0; t < 4; ++t) ib[t] = ib2[t];
                for (int t = 0; t < 6; ++t) sb[t] = sb2[t];
                nl[ns++] = rv;
            }
        }
        for (unsigned c = 1; c < 64 && ns < 6; ++c) {
            unsigned img = 0; unsigned short rv = 0;
            for (int i = 0; i < 6; ++i) if ((c >> i) & 1) { img ^= imu[i]; rv = (unsigned short)(rv ^ VC.lane[p][i]); }
            if (img != 0) continue;
            unsigned sb2[6] = {sb[0], sb[1], sb[2], sb[3], sb[4], sb[5]};
            if (add_basis6(sb2, c)) {
                for (int t = 0; t < 6; ++t) sb[t] = sb2[t];
                nl[ns++] = rv;
            }
        }
        if (ns == 6)
            for (int i = 0; i < 6; ++i) O.lane[p][i] = nl[i];
    }
    return O;
}
constexpr LaneOrd LO = build_lane2();

// pre-swizzled combo offsets
struct CS2 { unsigned short c[NP][NE]; };
constexpr CS2 build_cs2() {
    CS2 C{};
    for (int p = 0; p < NP; ++p)
        for (int j = 0; j < NE; ++j)
            C.c[p][j] = swz2(A.pass[p].comboR[j]);
    return C;
}
constexpr CS2 CSS = build_cs2();

// L'(j*512) for the init write
struct LJt { unsigned short v[NE]; };
constexpr LJt build_lj() {
    LJt t{};
    for (int j = 0; j < NE; ++j) t.v[j] = (unsigned short)lmap(LSEL.row, (unsigned)(j * THREADS));
    return t;
}
constexpr LJt LJ = build_lj();

// entry = (swz2(proj(vec))<<3) | (nongroup_parity_bits(9) << 22)
constexpr unsigned pack_entry(unsigned short vec0, int p) {
    const PassD& P = A.pass[p];
    unsigned short vec = proj(vec0, P);
    unsigned par = 0;
    if (P.rzidx >= 0)
        for (int t = 0; t < 9; ++t) par |= (unsigned)parity14(vec & A.rz[P.rzidx].rows_ng[t]) << t;
    if (P.measfold)
        for (int t = 0; t < 9; ++t) par |= (unsigned)parity14(vec & A.meas_rows_ng[t]) << t;
    return ((unsigned)swz2(vec) << 3) | (par << 22);
}

// LUT0: tid bits 0-4 (lane vecs 0-4); LUT1: tid bits 5-8 (lane vec 5 + wave g[0..2])
struct LutsT { unsigned v[NP][2][32]; };
constexpr LutsT build_luts() {
    LutsT L{};
    for (int p = 0; p < NP; ++p) {
        int k = p >> 1;
        for (int t = 0; t < 32; ++t) {
            unsigned short x = 0;
            for (int i = 0; i < 5; ++i) if ((t >> i) & 1) x = (unsigned short)(x ^ LO.lane[p][i]);
            L.v[p][0][t] = pack_entry(x, p);
        }
        for (int t = 0; t < 16; ++t) {
            unsigned short y = 0;
            if (t & 1) y = (unsigned short)(y ^ LO.lane[p][5]);
            for (int i = 0; i < 3; ++i) if ((t >> (i + 1)) & 1) y = (unsigned short)(y ^ VC.g[k][i]);
            L.v[p][1][t] = pack_entry(y, p);
        }
    }
    return L;
}
constexpr LutsT LUTS = build_luts();
__device__ __constant__ LutsT cLUTS = LUTS;

// ---------------- per-pass device code (canonical labels, packed-f32) ----------------
template<int Pi>
__device__ __forceinline__ void run_pass(f2* st, const f2 (*tabG)[8], const float (*tabRZ)[14],
                                         unsigned comb, float* acc)
{
    constexpr PassD Pd = A.pass[Pi];
    char* stb = (char*)st;
    const int base = (int)(comb & 0x1FFF8u);
    const unsigned par = comb >> 22;          // 9 non-group parity bits

    f2 v[NE];
#pragma unroll
    for (int j = 0; j < NE; ++j)
        v[j] = *(const f2*)(stb + (base ^ (CSS.c[Pi][j] << 3)));

    // ---- fused RZ layer (first pass of each block) ----
    if constexpr (Pd.rzidx >= 0) {
        float phi0 = 0.f;
#pragma unroll
        for (int t = 0; t < 9; ++t) {
            float h = tabRZ[Pd.rzidx][t];
            phi0 += ((par >> t) & 1) ? h : -h;
        }
        const float h0 = tabRZ[Pd.rzidx][9],  h1 = tabRZ[Pd.rzidx][10];
        const float h2 = tabRZ[Pd.rzidx][11], h3 = tabRZ[Pd.rzidx][12];
        const float h4 = tabRZ[Pd.rzidx][13];
#pragma unroll
        for (int j = 0; j < NE; ++j) {
            float phi = (((((phi0 + ((j & 1) ? h0 : -h0)) + ((j & 2) ? h1 : -h1))
                                  + ((j & 4) ? h2 : -h2)) + ((j & 8) ? h3 : -h3))
                                  + ((j & 16) ? h4 : -h4));
            float s, c; __sincosf(phi, &s, &c);
            f2 C = {c, c}, S = {-s, s};
            v[j] = C * v[j] + S * v[j].yx;
        }
    }

    // ---- CRX chain: control = tile bit g (logical), target = tile bit g+1 ----
#pragma unroll
    for (int g = 0; g < Pd.ncrx; ++g) {
        f2 cs = tabG[Pi][g];
        f2 C = {cs.x, cs.x}, S = {cs.y, -cs.y};
#pragma unroll
        for (int j = 0; j < NE; ++j) if (((j >> g) & 1) && !((j >> (g + 1)) & 1)) {
            int j1 = j | (1 << (g + 1));
            f2 a0 = v[j], a1 = v[j1];
            v[j]  = C * a0 + S * a1.yx;
            v[j1] = C * a1 + S * a0.yx;
        }
    }

    // ---- folded next-block RY gates ----
#pragma unroll
    for (int g = 0; g < Pd.nry; ++g) {
        int t = Pd.ry_tb[g];
        f2 cs = tabG[Pi][4 + g];
        f2 C = {cs.x, cs.x}, Sv = {cs.y, cs.y}, NS = {-cs.y, -cs.y};
#pragma unroll
        for (int j = 0; j < NE; ++j) if (!((j >> t) & 1)) {
            int j1 = j | (1 << t);
            f2 a0 = v[j], a1 = v[j1];
            v[j]  = C * a0 + NS * a1;
            v[j1] = Sv * a0 + C * a1;
        }
    }

    if constexpr (Pd.measfold != 0) {
        f2 ps = {0.f, 0.f}, p0 = {0.f, 0.f}, p1 = {0.f, 0.f}, p2 = {0.f, 0.f}, p3 = {0.f, 0.f}, p4 = {0.f, 0.f};
#pragma unroll
        for (int j = 0; j < NE; ++j) {
            f2 t2 = v[j] * v[j];
            ps += t2;
            if (j & 1)  p0 += t2;
            if (j & 2)  p1 += t2;
            if (j & 4)  p2 += t2;
            if (j & 8)  p3 += t2;
            if (j & 16) p4 += t2;
        }
        float psum = ps.x + ps.y;
        float pg0 = p0.x + p0.y, pg1 = p1.x + p1.y, pg2 = p2.x + p2.y;
        float pg3 = p3.x + p3.y, pg4 = p4.x + p4.y;
        // tile state bits {1,0,13,3,2} = JAX qubits {12,13,0,10,11}; group signs +1 (canonical)
        acc[12] += psum - 2.f * pg0;
        acc[13] += psum - 2.f * pg1;
        acc[0]  += psum - 2.f * pg2;
        acc[10] += psum - 2.f * pg3;
        acc[11] += psum - 2.f * pg4;
#pragma unroll
        for (int t = 0; t < 9; ++t) {
            float sg = ((par >> t) & 1) ? -1.f : 1.f;
            acc[1 + t] += sg * psum;
        }
    } else {
#pragma unroll
        for (int j = 0; j < NE; ++j)
            *(f2*)(stb + (base ^ (CSS.c[Pi][j] << 3))) = v[j];
        // wave-closed pairing: barrier only at end of each (even,odd) pair.
        if constexpr ((Pi & 1) != 0) __syncthreads();
    }
}

template<int... I>
__device__ __forceinline__ void run_all(std::integer_sequence<int, I...>,
                                        f2* st, const f2 (*tabG)[8], const float (*tabRZ)[14],
                                        const unsigned* comb, float* acc)
{
    (run_pass<I>(st, tabG, tabRZ, comb[I], acc), ...);
}

// ---------------- main kernel ----------------
// 512 threads, 32 elem/thread; 8 waves/CU (2/SIMD) -> VGPR cap 256 via launch_bounds.
__global__ __launch_bounds__(THREADS, 2)
void qsim_kernel(const float* __restrict__ inputs,
                 const float* __restrict__ weights,
                 float* __restrict__ out)
{
    __shared__ f2     st[NST];           // 128 KiB state
    __shared__ float  tab[256];
    __shared__ f2     tabG[NP][8];
    __shared__ float  tabRZ[4][14];      // 9 ng + 5 group half-angles
    __shared__ float  red[THREADS / 64][NQ];

    const int b = blockIdx.x;
    const int tid = threadIdx.x;

    unsigned comb[NP];
#pragma unroll
    for (int p = 0; p < NP; ++p)
        comb[p] = cLUTS.v[p][0][tid & 31] ^ cLUTS.v[p][1][tid >> 5];

    // ---- build trig + product tables (disjoint thread ranges) ----
    if (tid < 128) {
        int p = tid >> 3, sl = tid & 7;
        float w = weights[GW.w[p][sl]];
        float s, c; __sincosf(0.5f * w, &s, &c);
        tabG[p][sl] = (f2){c, s};
    } else if (tid >= 128 && tid < 128 + 56) {
        int idx = tid - 128;
        int blk = idx / 14, k = idx - blk * 14;
        unsigned wi = (k < 9) ? A.rz[blk].widx_ng[k] : A.rz[blk].widx_g[k - 9];
        tabRZ[blk][k] = 0.5f * weights[wi];
    } else if (tid >= 256) {
        int t = tid - 256;
        int half = t >> 7, tt = t & 127;
        float prod = 1.f;
#pragma unroll
        for (int j = 0; j < 7; ++j) {
            int xb = j + 7 * half;
            int q  = 13 - xb;
            float a = 0.5f * (inputs[b * NQ + q] + weights[q]);   // init RY ∘ blk0 RY fold
            float s, c; __sincosf(a, &s, &c);
            prod *= ((tt >> j) & 1) ? s : c;
        }
        tab[t] = prod;
    }
    __syncthreads();

    // ---- write product state with swz2 ----
    unsigned l4t = 0;
#pragma unroll
    for (int t = 0; t < 4; ++t)
        l4t |= (unsigned)(__popc((int)(LSEL.row[t] & tid)) & 1) << t;
#pragma unroll
    for (int j = 0; j < NE; ++j) {
        int x = tid + j * THREADS;
        int addr = (x & ~15) | (int)(l4t ^ LJ.v[j]);
        st[addr] = (f2){tab[x & 127] * tab[128 + (x >> 7)], 0.f};
    }
    __syncthreads();

    float acc[NQ];
#pragma unroll
    for (int q = 0; q < NQ; ++q) acc[q] = 0.f;

    run_all(std::make_integer_sequence<int, NP>{}, st, tabG, tabRZ, comb, acc);

    // ---- block-wide reduction ----
#pragma unroll
    for (int q = 0; q < NQ; ++q) {
        float v2 = acc[q];
        v2 += __shfl_down(v2, 32);
        v2 += __shfl_down(v2, 16);
        v2 += __shfl_down(v2, 8);
        v2 += __shfl_down(v2, 4);
        v2 += __shfl_down(v2, 2);
        v2 += __shfl_down(v2, 1);
        acc[q] = v2;
    }
    const int wave = tid >> 6, lane = tid & 63;
    if (lane == 0) {
#pragma unroll
        for (int q = 0; q < NQ; ++q) red[wave][q] = acc[q];
    }
    __syncthreads();
    if (tid < NQ) {
        float v2 = 0.f;
#pragma unroll
        for (int w = 0; w < THREADS / 64; ++w) v2 += red[w][tid];
        out[b * NQ + tid] = v2;
    }
}

extern "C" void kernel_launch(void* const* d_in, const int* in_sizes, int n_in,
                              void* d_out, int out_size, void* d_ws, size_t ws_size,
                              hipStream_t stream) {
    const float* inputs  = (const float*)d_in[0];
    const float* weights = (const float*)d_in[1];
    float* out = (float*)d_out;
    const int B = in_sizes[0] / NQ;   // 256
    qsim_kernel<<<dim3(B), dim3(THREADS), 0, stream>>>(inputs, weights, out);
}